// Round 9
// baseline (461.255 us; speedup 1.0000x reference)
//
#include <hip/hip_runtime.h>
#include <hip/hip_bf16.h>

typedef unsigned short u16;
typedef unsigned int u32;
typedef short short8v __attribute__((ext_vector_type(8)));
typedef float f32x4 __attribute__((ext_vector_type(4)));
typedef u32 u32x4 __attribute__((ext_vector_type(4)));

#define NN 50000
#define EE 800000
#define PP 65536
#define NBKT 196      // node buckets of 256: ceil(NN/256)
#define NHB 256       // histogram blocks (edge chunks of 3125)
#define ECH 3125      // edges per histogram block: 256*3125 = EE exactly

// ---- static device workspace. RULE (r3): device-global addresses never cross
// the host/device boundary — kernels resolve them via compile-time IDs.
// RULE (r15): NO cooperative launch / grid.sync on this chip.
// RULE (r22): fused producer->consumer kernels must write into buffers that NO
// other block still reads (r4/r5 failed on a phaseB-writes-alias-phaseA-reads
// race: Z buffers sat on g_H1/g_H2 while other blocks' GEMM still read them).
__device__ __align__(256) float g_deg_norm[NN];
__device__ __align__(256) int   g_row_ptr[NN + 1];
__device__ __align__(256) int   g_rank[EE];          // intra-node rank
__device__ __align__(256) int   g_bh[NBKT * NHB];    // [bucket][block] counts
__device__ __align__(256) int   g_bbase[NBKT * NHB]; // exclusive scan over blocks
__device__ __align__(256) int   g_btot[NBKT];
__device__ __align__(256) u32   g_ebkt[EE];          // bucket-grouped: src | dlow<<16
__device__ __align__(256) float g_wtmp[EE];          // raw w (f32), bucket-grouped
__device__ __align__(256) float g_w2[EE];            // raw w, CSR order
__device__ __align__(256) u32   g_ecwp[EE];          // final: src(16b) | w_bf16(16b)
__device__ __align__(256) u16   g_X16[NN * 128];     // x bf16; after gemm1: Z1|Z0
__device__ __align__(256) u16   g_H1[NN * 128];      // hop outs
__device__ __align__(256) u16   g_H2[NN * 128];
__device__ __align__(256) u16   g_H3[NN * 128];      // hop out; later T ping|pong
__device__ __align__(256) u16   g_Hn0[NN * 128];
__device__ __align__(256) u16   g_Hn1[NN * 128];     // Z3|Z2 (gemm2z output only)
__device__ __align__(256) u16   g_Hf16[NN * 64];     // final h (bf16), row-major
__device__ __align__(256) u16   g_Bf1[512 * 128];    // W in MFMA B-fragment order
__device__ __align__(256) u16   g_Bf2[512 * 128];
__device__ __align__(256) u16   g_Bf3[512 * 64];
__device__ __align__(256) u16   g_Pf1[4 * 64 * 8];   // P1 in B-frag order
__device__ int g_f32mode;  // 1 if harness float tensors are float32, 0 if bf16

__device__ __forceinline__ float bf2f(u16 u) {
  union { u32 i; float f; } v;
  v.i = ((u32)u) << 16;
  return v.f;
}
__device__ __forceinline__ u16 f2bf(float f) {
  u32 x = __float_as_uint(f);
  u32 r = (x + 0x7fffu + ((x >> 16) & 1u)) >> 16;  // RNE
  return (u16)r;
}
__device__ __forceinline__ float ldf(const void* p, int i, int m) {
  return m ? ((const float*)p)[i] : bf2f(((const u16*)p)[i]);
}

// buffer IDs: 0 = X16, 3 = Hn0, 5 = H1, 6 = H2, 7 = H3 (stride 128)
template <int ID>
__device__ __forceinline__ u16* sel_buf() {
  if (ID == 0) return g_X16;
  if (ID == 3) return g_Hn0;
  if (ID == 5) return g_H1;
  if (ID == 6) return g_H2;
  return g_H3;
}
template <int ID>
__device__ __forceinline__ u16* sel_bf() {
  if (ID == 1) return g_Bf1;
  if (ID == 2) return g_Bf2;
  return g_Bf3;
}
// width-64 Z/T buffers for layer-3 Horner.
// r22 alias-free mapping: Z3/Z2 on g_Hn1 (dead: gemm2z keeps Hn1-tile in LDS),
// Z1/Z0 on g_X16 (dead after layer-1 GEMM), T ping/pong on g_H3 (dead after
// gemm2z reads it; first T write happens a launch AFTER gemm2z completes).
template <int ID>
__device__ __forceinline__ u16* zb() {
  if (ID == 8) return g_Hn1;                // Z3
  if (ID == 9) return g_Hn1 + NN * 64;      // Z2
  if (ID == 10) return g_X16;               // Z1
  if (ID == 11) return g_X16 + NN * 64;     // Z0 (+bias)
  if (ID == 12) return g_H3;                // T ping
  return g_H3 + NN * 64;                    // 13: T pong
}

// ---- per-block dtype vote (replaces probe_dtype kernel; r22).
// 256 samples of x's even u16 elements: f32 mode -> low-mantissa bits look
// uniform, (u>>7)&0xFF >= 0x8F with p~0.44 (exp ~113 hits); bf16 N(0,1) -> 0.
// Deterministic and identical across blocks.
__device__ __forceinline__ int vote_f32mode(const u16* __restrict__ x, int tid, int* vcnt) {
  if (tid == 0) *vcnt = 0;
  __syncthreads();
  u16 u = x[2 * (tid * 8)];
  if (((u >> 7) & 0xFF) >= 0x8F) atomicAdd(vcnt, 1);
  __syncthreads();
  return (*vcnt > 28) ? 1 : 0;
}

// ---------------- fused prep1: dtype vote | x->bf16 | bucket hist | W/P convert
template <int FOUT>
__device__ __forceinline__ void conv_w_body(const void* W, u16* dstbuf, int t, int m) {
  constexpr int NT = FOUT / 16;
  if (t >= 1024 * NT) return;
  int lane = t & 63;
  int rest = t >> 6;
  int nt = rest % NT;
  int s = (rest / NT) % 4;
  int kc = rest / (NT * 4);
  int kbase = kc * 128 + s * 32 + ((lane >> 4) << 3);
  int n = nt * 16 + (lane & 15);
  u16* dst = dstbuf + (size_t)t * 8;
#pragma unroll
  for (int j = 0; j < 8; ++j) dst[j] = f2bf(ldf(W, (kbase + j) * FOUT + n, m));
}
__global__ void prep1_kernel(const void* __restrict__ xv, const int* __restrict__ dst,
                             const void* __restrict__ W1, const void* __restrict__ W2,
                             const void* __restrict__ W3, const void* __restrict__ P1) {
  __shared__ int lhist[NBKT];
  __shared__ int vcnt;
  const u16* x = (const u16*)xv;
  int b = blockIdx.x, tid = threadIdx.x;
  int m = vote_f32mode(x, tid, &vcnt);
  if (b == 0 && tid == 0) g_f32mode = m;  // publish for downstream launches
  if (b < 12500) {
    int i = b * 256 + tid;  // u32-pair index, exact: 12500*256 = NN*64
    u32 lo = f2bf(ldf(x, 2 * i, m));
    u32 hi = f2bf(ldf(x, 2 * i + 1, m));
    ((u32*)g_X16)[i] = lo | (hi << 16);
  } else if (b < 12500 + NHB) {
    int hb = b - 12500;
    for (int i = tid; i < NBKT; i += 256) lhist[i] = 0;
    __syncthreads();
    int base = hb * ECH;
    for (int i = tid; i < ECH; i += 256) atomicAdd(&lhist[dst[base + i] >> 8], 1);
    __syncthreads();
    if (tid < NBKT) g_bh[tid * NHB + hb] = lhist[tid];
  } else {
    int wb = b - (12500 + NHB);
    if (wb < 32) {
      conv_w_body<128>(W1, g_Bf1, wb * 256 + tid, m);
    } else if (wb < 64) {
      conv_w_body<128>(W2, g_Bf2, (wb - 32) * 256 + tid, m);
    } else if (wb < 80) {
      conv_w_body<64>(W3, g_Bf3, (wb - 64) * 256 + tid, m);
    } else {
      int f = tid >> 6, lane = tid & 63;
      int ks = f >> 1, nt = f & 1;
      int quad = lane >> 4, arow = lane & 15;
#pragma unroll
      for (int j = 0; j < 8; ++j)
        g_Pf1[(size_t)tid * 8 + j] =
            f2bf(ldf(P1, (ks * 32 + quad * 8 + j) * 32 + nt * 16 + arow, m));
    }
  }
}

// ------------------------------------- S2: per-bucket exclusive scan over blocks
__global__ __launch_bounds__(256) void bucket_scan_kernel() {
  __shared__ int ws[4];
  int g = blockIdx.x, t = threadIdx.x;
  int v = g_bh[g * NHB + t];
  int x = v;
#pragma unroll
  for (int off = 1; off < 64; off <<= 1) {
    int y = __shfl_up(x, off, 64);
    if ((t & 63) >= off) x += y;
  }
  if ((t & 63) == 63) ws[t >> 6] = x;
  __syncthreads();
  int wp = 0;
  if (t >= 64) wp += ws[0];
  if (t >= 128) wp += ws[1];
  if (t >= 192) wp += ws[2];
  g_bbase[g * NHB + t] = wp + x - v;  // exclusive within bucket, block order
  if (t == 255) g_btot[g] = wp + x;
}

// --- local bucket-start scan helper: exclusive scan of g_btot into sb[] (LDS)
__device__ __forceinline__ void local_bstart(int* sb, int* ws, int tid) {
  int v = (tid < NBKT) ? g_btot[tid] : 0;
  int x = v;
#pragma unroll
  for (int off = 1; off < 64; off <<= 1) {
    int y = __shfl_up(x, off, 64);
    if ((tid & 63) >= off) x += y;
  }
  if ((tid & 63) == 63) ws[tid >> 6] = x;
  __syncthreads();
  int wp = 0;
  if (tid >= 64) wp += ws[0];
  if (tid >= 128) wp += ws[1];
  if (tid >= 192) wp += ws[2];
  if (tid < NBKT) sb[tid] = wp + x - v;
  if (tid == 0) sb[NBKT] = EE;
  __syncthreads();
}

// ---------------------------- S4: scatter edges into bucket-grouped order
__global__ __launch_bounds__(256) void scatter_bucket_kernel(const int* __restrict__ src,
                                                             const int* __restrict__ dst,
                                                             const void* __restrict__ w_edge) {
  __shared__ int sb[NBKT + 1];
  __shared__ int ws[4];
  __shared__ int lhist[NBKT];
  __shared__ int lbase[NBKT];
  int m = g_f32mode;
  int b = blockIdx.x, tid = threadIdx.x;
  local_bstart(sb, ws, tid);
  for (int i = tid; i < NBKT; i += 256) {
    lhist[i] = 0;
    lbase[i] = sb[i] + g_bbase[i * NHB + b];
  }
  __syncthreads();
  int base = b * ECH;
  for (int i = tid; i < ECH; i += 256) {
    int e = base + i;
    int d = dst[e];
    int s = src[e];
    float w = ldf(w_edge, e, m);
    int bkt = d >> 8;
    int r = atomicAdd(&lhist[bkt], 1);
    int pos = lbase[bkt] + r;
    g_ebkt[pos] = (u32)s | ((u32)(d & 255) << 16);
    g_wtmp[pos] = w;
  }
}

// ------------- S5: per-bucket CSR finalize: 256-bin LDS hist -> row_ptr,
// deg_norm, and in-bucket scatter to exact per-node segments.
__global__ __launch_bounds__(256) void csr_finalize_kernel() {
  __shared__ int sb[NBKT + 1];
  __shared__ int ws[4];
  __shared__ int hist[256];
  __shared__ int loff[256];
  int g = blockIdx.x, t = threadIdx.x;
  local_bstart(sb, ws, t);
  int bs = sb[g], be = sb[g + 1];
  hist[t] = 0;
  __syncthreads();
  for (int i = bs + t; i < be; i += 256) {
    int dlow = (g_ebkt[i] >> 16) & 0xFF;
    g_rank[i] = atomicAdd(&hist[dlow], 1);
  }
  __syncthreads();
  int v = hist[t];
  int x = v;
#pragma unroll
  for (int off = 1; off < 64; off <<= 1) {
    int y = __shfl_up(x, off, 64);
    if ((t & 63) >= off) x += y;
  }
  if ((t & 63) == 63) ws[t >> 6] = x;
  __syncthreads();
  int wp = 0;
  if (t >= 64) wp += ws[0];
  if (t >= 128) wp += ws[1];
  if (t >= 192) wp += ws[2];
  int excl = wp + x - v;
  loff[t] = excl;
  int node = g * 256 + t;
  if (node < NN) {
    g_row_ptr[node] = bs + excl;
    g_deg_norm[node] = rsqrtf((float)(v > 0 ? v : 1));
  }
  if (g == NBKT - 1 && t == 0) g_row_ptr[NN] = EE;
  __syncthreads();
  for (int i = bs + t; i < be; i += 256) {
    u32 p = g_ebkt[i];
    int dlow = (p >> 16) & 0xFF;
    int pos = bs + loff[dlow] + g_rank[i];
    g_ecwp[pos] = p;       // src in low 16; w field written by hop1 (FINW)
    g_w2[pos] = g_wtmp[i];
  }
}

// --------------------------------------------------------- width-128 hop (r21)
// out[n][f] = deg_norm[n] * sum_e w[e] * in[col[e]][f]
// ONE 16-LANE GROUP PER NODE (4 nodes/wave); per-lane register accumulators,
// no cross-lane reduction, one 16B store per lane. (r21-proven, -23us)
template <int IN_ID, int OUT_ID, bool FINW>
__global__ __launch_bounds__(256) void hop_kernel() {
  int lane = threadIdx.x & 63;
  int wv = threadIdx.x >> 6;
  int grp = lane >> 4;  // node slot in wave
  int q = lane & 15;    // feature block
  int n = blockIdx.x * 16 + wv * 4 + grp;  // NN%16==0 -> no OOB (grid exact)
  const u16* inf = sel_buf<IN_ID>() + q * 8;
  int beg = g_row_ptr[n], end = g_row_ptr[n + 1];
  int sl = grp << 4;  // shfl base lane of this group
  float a[8];
#pragma unroll
  for (int j = 0; j < 8; ++j) a[j] = 0.f;
  for (int c = beg; c < end; c += 16) {
    int cnt = end - c;
    if (cnt > 16) cnt = 16;
    u32 myp = 0;
    float wf = 0.f;
    if (q < cnt) {
      myp = g_ecwp[c + q];
      if (FINW) {
        wf = g_w2[c + q] * g_deg_norm[myp & 0xFFFFu];
        g_ecwp[c + q] = (myp & 0xFFFFu) | ((u32)f2bf(wf) << 16);
      } else {
        wf = bf2f((u16)(myp >> 16));
      }
    }
    int i = 0;
    for (; i + 4 <= cnt; i += 4) {
      u32 p0 = __shfl(myp, sl + i, 64);
      u32 p1 = __shfl(myp, sl + i + 1, 64);
      u32 p2 = __shfl(myp, sl + i + 2, 64);
      u32 p3 = __shfl(myp, sl + i + 3, 64);
      float w0 = __shfl(wf, sl + i, 64);
      float w1 = __shfl(wf, sl + i + 1, 64);
      float w2 = __shfl(wf, sl + i + 2, 64);
      float w3 = __shfl(wf, sl + i + 3, 64);
      short8v u0 = *(const short8v*)(inf + (p0 & 0xFFFFu) * 128);
      short8v u1 = *(const short8v*)(inf + (p1 & 0xFFFFu) * 128);
      short8v u2 = *(const short8v*)(inf + (p2 & 0xFFFFu) * 128);
      short8v u3 = *(const short8v*)(inf + (p3 & 0xFFFFu) * 128);
#pragma unroll
      for (int j = 0; j < 8; ++j) {
        a[j] += w0 * bf2f((u16)u0[j]);
        a[j] += w1 * bf2f((u16)u1[j]);
        a[j] += w2 * bf2f((u16)u2[j]);
        a[j] += w3 * bf2f((u16)u3[j]);
      }
    }
    for (; i < cnt; ++i) {
      u32 p = __shfl(myp, sl + i, 64);
      float w = __shfl(wf, sl + i, 64);
      short8v u = *(const short8v*)(inf + (p & 0xFFFFu) * 128);
#pragma unroll
      for (int j = 0; j < 8; ++j) a[j] += w * bf2f((u16)u[j]);
    }
  }
  float dn = g_deg_norm[n];
  u32x4 o;
#pragma unroll
  for (int j = 0; j < 4; ++j)
    o[j] = (u32)f2bf(a[2 * j] * dn) | ((u32)f2bf(a[2 * j + 1] * dn) << 16);
  *(u32x4*)(sel_buf<OUT_ID>() + n * 128 + q * 8) = o;  // 16B/lane, 1KB/wave
}

// ------------------------------------------------- width-64 hop with addend
// T_out[n] = deg_norm[n] * (A T_in)[n] + Add[n]   (layer-3 Horner step)
template <int IN_ID, int ADD_ID, int OUT_ID, bool FINAL>
__global__ __launch_bounds__(256) void hop64_kernel(void* __restrict__ outp) {
  int lane = threadIdx.x & 63;
  int wv = threadIdx.x >> 6;
  int grp = lane >> 3;  // node slot 0..7
  int q = lane & 7;     // feature block (8 x 8 = 64 feats)
  int n = blockIdx.x * 32 + wv * 8 + grp;
  if (n >= NN) return;  // no barriers -> safe
  const u16* inf = zb<IN_ID>() + q * 8;
  int beg = g_row_ptr[n], end = g_row_ptr[n + 1];
  int sl = grp << 3;
  float a[8];
#pragma unroll
  for (int j = 0; j < 8; ++j) a[j] = 0.f;
  for (int c = beg; c < end; c += 8) {
    int cnt = end - c;
    if (cnt > 8) cnt = 8;
    u32 myp = 0;
    float wf = 0.f;
    if (q < cnt) {
      myp = g_ecwp[c + q];
      wf = bf2f((u16)(myp >> 16));
    }
    int i = 0;
    for (; i + 4 <= cnt; i += 4) {
      u32 p0 = __shfl(myp, sl + i, 64);
      u32 p1 = __shfl(myp, sl + i + 1, 64);
      u32 p2 = __shfl(myp, sl + i + 2, 64);
      u32 p3 = __shfl(myp, sl + i + 3, 64);
      float w0 = __shfl(wf, sl + i, 64);
      float w1 = __shfl(wf, sl + i + 1, 64);
      float w2 = __shfl(wf, sl + i + 2, 64);
      float w3 = __shfl(wf, sl + i + 3, 64);
      short8v u0 = *(const short8v*)(inf + (p0 & 0xFFFFu) * 64);
      short8v u1 = *(const short8v*)(inf + (p1 & 0xFFFFu) * 64);
      short8v u2 = *(const short8v*)(inf + (p2 & 0xFFFFu) * 64);
      short8v u3 = *(const short8v*)(inf + (p3 & 0xFFFFu) * 64);
#pragma unroll
      for (int j = 0; j < 8; ++j) {
        a[j] += w0 * bf2f((u16)u0[j]);
        a[j] += w1 * bf2f((u16)u1[j]);
        a[j] += w2 * bf2f((u16)u2[j]);
        a[j] += w3 * bf2f((u16)u3[j]);
      }
    }
    for (; i < cnt; ++i) {
      u32 p = __shfl(myp, sl + i, 64);
      float w = __shfl(wf, sl + i, 64);
      short8v u = *(const short8v*)(inf + (p & 0xFFFFu) * 64);
#pragma unroll
      for (int j = 0; j < 8; ++j) a[j] += w * bf2f((u16)u[j]);
    }
  }
  float dn = g_deg_norm[n];
  int ci = n * 64 + q * 8;
  u32x4 ad = *(const u32x4*)(zb<ADD_ID>() + ci);
  float r[8];
#pragma unroll
  for (int j = 0; j < 4; ++j) {
    r[2 * j] = a[2 * j] * dn + bf2f((u16)ad[j]);
    r[2 * j + 1] = a[2 * j + 1] * dn + bf2f((u16)(ad[j] >> 16));
  }
  u32x4 o;
#pragma unroll
  for (int j = 0; j < 4; ++j)
    o[j] = (u32)f2bf(r[2 * j]) | ((u32)f2bf(r[2 * j + 1]) << 16);
  if (!FINAL) {
    *(u32x4*)(zb<OUT_ID>() + ci) = o;
  } else {
    *(u32x4*)(g_Hf16 + ci) = o;
    if (g_f32mode) {
#pragma unroll
      for (int j = 0; j < 8; ++j) ((float*)outp)[2 * PP + ci + j] = r[j];
    } else {
      *(u32x4*)((u16*)outp + 2 * PP + ci) = o;
    }
  }
}

// -------------------------------------------------- MFMA GEMM (FOUT=128)
// C(M x 128) = [f0 | H1 | H2 | H3] (Mx512, row-major) @ B + bias, ReLU.
// Used for layer 1 only (writes Hn0 to global).
template <int A0_ID, int C_ID, int BF_ID>
__global__ __launch_bounds__(256) void gemm_kernel(const void* __restrict__ bias) {
  constexpr int NT = 8;
  const u16* Bf = sel_bf<BF_ID>();
  int tid = threadIdx.x;
  int lane = tid & 63, wv = tid >> 6;
  int quad = lane >> 4, arow = lane & 15;
  int mbase = blockIdx.x * 64 + wv * 16;
  if (mbase >= NN) return;  // no barriers -> safe (NN % 16 == 0)
  int row0 = mbase + arow;

  f32x4 acc[NT];
#pragma unroll
  for (int nt = 0; nt < NT; ++nt) acc[nt] = (f32x4){0.f, 0.f, 0.f, 0.f};

#pragma unroll
  for (int kc = 0; kc < 4; ++kc) {
    const u16* base = (kc == 0) ? sel_buf<A0_ID>() : (kc == 1) ? g_H1 : (kc == 2) ? g_H2 : g_H3;
#pragma unroll
    for (int s = 0; s < 4; ++s) {
      int ko = s * 32 + quad * 8;
      short8v av = *(const short8v*)(base + row0 * 128 + ko);
      const u16* bp = Bf + (size_t)(((kc * 4 + s) * NT) * 64 + lane) * 8;
#pragma unroll
      for (int nt = 0; nt < NT; ++nt) {
        short8v b = *(const short8v*)(bp + nt * 64 * 8);
        acc[nt] = __builtin_amdgcn_mfma_f32_16x16x32_bf16(av, b, acc[nt], 0, 0, 0);
      }
    }
  }

  int m = g_f32mode;
  float bn[NT];
#pragma unroll
  for (int nt = 0; nt < NT; ++nt) bn[nt] = ldf(bias, nt * 16 + arow, m);
#pragma unroll
  for (int i = 0; i < 4; ++i) {
    int row = mbase + quad * 4 + i;  // C/D: col=lane&15, row=quad*4+reg
#pragma unroll
    for (int nt = 0; nt < NT; ++nt) {
      float v = acc[nt][i] + bn[nt];
      v = v > 0.f ? v : 0.f;  // ReLU
      sel_buf<C_ID>()[row * 128 + nt * 16 + arow] = f2bf(v);
    }
  }
}

// ------------------ fused layer-2 GEMM + Z_k GEMMs (r22, alias-fixed)
// Phase A: Hn1-tile = ReLU([Hn0|H1|H2|H3] @ W2 + b2) for this wave's 16 rows,
// staged in the wave's own LDS slice (never hits global).
// Phase B: Z_k = Hn1-tile @ W3[kc] (+b3 for k=0) -> Z3/Z2 on g_Hn1, Z1/Z0 on
// g_X16 — buffers NO phase-A reader touches (the r4/r5 race wrote onto
// g_H1/g_H2 which other blocks' phase A was still reading).
// No early return: all 256 threads reach __syncthreads; compute guarded.
__global__ __launch_bounds__(256) void gemm2z_kernel(const void* __restrict__ bias2,
                                                     const void* __restrict__ bias3) {
  __shared__ __align__(16) u16 lt[4][16][136];  // 136 = 128 + 8 pad (272B rows, 16B-mult)
  constexpr int NT = 8;
  int tid = threadIdx.x;
  int lane = tid & 63, wv = tid >> 6;
  int quad = lane >> 4, arow = lane & 15;
  int mbase = blockIdx.x * 64 + wv * 16;
  bool active = (mbase < NN);  // NN % 16 == 0
  int row0 = mbase + arow;
  int m = g_f32mode;

  // ---- phase A: layer-2 GEMM into own LDS slice ----
  if (active) {
    f32x4 acc[NT];
#pragma unroll
    for (int nt = 0; nt < NT; ++nt) acc[nt] = (f32x4){0.f, 0.f, 0.f, 0.f};
#pragma unroll
    for (int kc = 0; kc < 4; ++kc) {
      const u16* base = (kc == 0) ? g_Hn0 : (kc == 1) ? g_H1 : (kc == 2) ? g_H2 : g_H3;
#pragma unroll
      for (int s = 0; s < 4; ++s) {
        int ko = s * 32 + quad * 8;
        short8v av = *(const short8v*)(base + row0 * 128 + ko);
        const u16* bp = g_Bf2 + (size_t)(((kc * 4 + s) * NT) * 64 + lane) * 8;
#pragma unroll
        for (int nt = 0; nt < NT; ++nt) {
          short8v b = *(const short8v*)(bp + nt * 64 * 8);
          acc[nt] = __builtin_amdgcn_mfma_f32_16x16x32_bf16(av, b, acc[nt], 0, 0, 0);
        }
      }
    }
    float bn[NT];
#pragma unroll
    for (int nt = 0; nt < NT; ++nt) bn[nt] = ldf(bias2, nt * 16 + arow, m);
#pragma unroll
    for (int i = 0; i < 4; ++i) {
#pragma unroll
      for (int nt = 0; nt < NT; ++nt) {
        float v = acc[nt][i] + bn[nt];
        v = v > 0.f ? v : 0.f;  // ReLU
        lt[wv][quad * 4 + i][nt * 16 + arow] = f2bf(v);
      }
    }
  }
  __syncthreads();  // orders LDS writes before reads; all 256 threads arrive

  // ---- phase B: Z_k = tile @ W3[kc] ----
  if (active) {
    f32x4 az[4][4];  // [kc][nt]
#pragma unroll
    for (int kc = 0; kc < 4; ++kc)
#pragma unroll
      for (int nt = 0; nt < 4; ++nt) az[kc][nt] = (f32x4){0.f, 0.f, 0.f, 0.f};
#pragma unroll
    for (int s = 0; s < 4; ++s) {
      short8v av = *(const short8v*)&lt[wv][arow][s * 32 + quad * 8];
#pragma unroll
      for (int kc = 0; kc < 4; ++kc) {
        const u16* bp = g_Bf3 + (size_t)(((kc * 4 + s) * 4) * 64 + lane) * 8;
#pragma unroll
        for (int nt = 0; nt < 4; ++nt) {
          short8v b = *(const short8v*)(bp + nt * 64 * 8);
          az[kc][nt] = __builtin_amdgcn_mfma_f32_16x16x32_bf16(av, b, az[kc][nt], 0, 0, 0);
        }
      }
    }
    float b3n[4];
#pragma unroll
    for (int nt = 0; nt < 4; ++nt) b3n[nt] = ldf(bias3, nt * 16 + arow, m);
#pragma unroll
    for (int kc = 0; kc < 4; ++kc) {
      u16* Z = (kc == 0) ? zb<11>() : (kc == 1) ? zb<10>() : (kc == 2) ? zb<9>() : zb<8>();
#pragma unroll
      for (int i = 0; i < 4; ++i) {
        int row = mbase + quad * 4 + i;
#pragma unroll
        for (int nt = 0; nt < 4; ++nt) {
          float v = az[kc][nt][i] + (kc == 0 ? b3n[nt] : 0.f);
          Z[row * 64 + nt * 16 + arow] = f2bf(v);
        }
      }
    }
  }
}

// ------------------------------------------------------------------ predictor
__global__ __launch_bounds__(256) void predictor_kernel(
    const int* __restrict__ pos_src, const int* __restrict__ pos_dst,
    const int* __restrict__ neg_src, const int* __restrict__ neg_dst,
    const void* __restrict__ pb1, const void* __restrict__ P2,
    const void* __restrict__ pb2, const void* __restrict__ P3, const void* __restrict__ pb3,
    void* __restrict__ out) {
  __shared__ float sP2[32 * 16];
  __shared__ float sb1[32], sb2[16], sP3[16];
  __shared__ float sb3;
  __shared__ float zt[4][16][33];
  int m = g_f32mode;
  int tid = threadIdx.x;
  for (int i = tid; i < 512; i += 256) sP2[i] = ldf(P2, i, m);
  if (tid < 32) sb1[tid] = ldf(pb1, tid, m);
  if (tid < 16) sb2[tid] = ldf(pb2, tid, m);
  if (tid < 16) sP3[tid] = ldf(P3, tid, m);
  if (tid == 0) sb3 = ldf(pb3, 0, m);
  __syncthreads();

  int wv = tid >> 6, lane = tid & 63;
  int quad = lane >> 4, arow = lane & 15;
  int base = (blockIdx.x * 4 + wv) * 16;
  int idx = base + arow;
  int s, d;
  if (idx < PP) { s = pos_src[idx]; d = pos_dst[idx]; }  // PP%16==0 -> wave-uniform
  else          { s = neg_src[idx - PP]; d = neg_dst[idx - PP]; }

  const u16* hs = g_Hf16 + s * 64 + quad * 8;
  const u16* hd = g_Hf16 + d * 64 + quad * 8;
  short8v zf[2];
#pragma unroll
  for (int ks = 0; ks < 2; ++ks) {
    short8v a = *(const short8v*)(hs + ks * 32);
    short8v b = *(const short8v*)(hd + ks * 32);
#pragma unroll
    for (int j = 0; j < 8; ++j)
      ((u16*)&zf[ks])[j] = f2bf(bf2f((u16)a[j]) * bf2f((u16)b[j]));
  }
  f32x4 acc[2];
  acc[0] = (f32x4){0.f, 0.f, 0.f, 0.f};
  acc[1] = (f32x4){0.f, 0.f, 0.f, 0.f};
#pragma unroll
  for (int ks = 0; ks < 2; ++ks) {
#pragma unroll
    for (int nt = 0; nt < 2; ++nt) {
      short8v bfr = *(const short8v*)(g_Pf1 + (size_t)((ks * 2 + nt) * 64 + lane) * 8);
      acc[nt] = __builtin_amdgcn_mfma_f32_16x16x32_bf16(zf[ks], bfr, acc[nt], 0, 0, 0);
    }
  }
#pragma unroll
  for (int nt = 0; nt < 2; ++nt) {
    float bn = sb1[nt * 16 + arow];
#pragma unroll
    for (int i = 0; i < 4; ++i) {
      float v = acc[nt][i] + bn;
      zt[wv][quad * 4 + i][nt * 16 + arow] = v > 0.f ? v : 0.2f * v;
    }
  }
  __syncthreads();
  float z2[4];
#pragma unroll
  for (int jj = 0; jj < 4; ++jj) z2[jj] = sb2[quad * 4 + jj];
  const float* zrow = &zt[wv][arow][0];
#pragma unroll
  for (int c = 0; c < 32; ++c) {
    float zc = zrow[c];
#pragma unroll
    for (int jj = 0; jj < 4; ++jj) z2[jj] += zc * sP2[c * 16 + quad * 4 + jj];
  }
  float o = 0.f;
#pragma unroll
  for (int jj = 0; jj < 4; ++jj) {
    float v = z2[jj] > 0.f ? z2[jj] : 0.2f * z2[jj];
    o += v * sP3[quad * 4 + jj];
  }
  o += __shfl_xor(o, 16, 64);
  o += __shfl_xor(o, 32, 64);
  o += sb3;
  if (quad == 0) {
    if (m) ((float*)out)[idx] = o;
    else   ((u16*)out)[idx] = f2bf(o);
  }
}

// ------------------------------------------------------------------- launch
extern "C" void kernel_launch(void* const* d_in, const int* in_sizes, int n_in,
                              void* d_out, int out_size, void* d_ws, size_t ws_size,
                              hipStream_t stream) {
  const void* x      = d_in[0];
  const int* src     = (const int*)d_in[1];
  const int* dst     = (const int*)d_in[2];
  const void* w_edge = d_in[3];
  const int* pos_src = (const int*)d_in[4];
  const int* pos_dst = (const int*)d_in[5];
  const int* neg_src = (const int*)d_in[6];
  const int* neg_dst = (const int*)d_in[7];
  const void* W1 = d_in[8];
  const void* b1 = d_in[9];
  const void* W2 = d_in[10];
  const void* b2 = d_in[11];
  const void* W3 = d_in[12];
  const void* b3 = d_in[13];
  const void* P1  = d_in[14];
  const void* pb1 = d_in[15];
  const void* P2  = d_in[16];
  const void* pb2 = d_in[17];
  const void* P3  = d_in[18];
  const void* pb3 = d_in[19];
  (void)d_ws; (void)ws_size; (void)in_sizes; (void)n_in; (void)out_size;

  // --- atomic-free CSR build; dtype vote folded into prep1 (r22) ---
  prep1_kernel<<<12500 + NHB + 81, 256, 0, stream>>>(x, dst, W1, W2, W3, P1);
  bucket_scan_kernel<<<NBKT, 256, 0, stream>>>();
  scatter_bucket_kernel<<<NHB, 256, 0, stream>>>(src, dst, w_edge);
  csr_finalize_kernel<<<NBKT, 256, 0, stream>>>();

  int gHop = NN / 16;            // 3125, exact (16 nodes/block)
  int gHop64 = (NN + 31) / 32;   // 1563 (32 nodes/block)
  int gGemm = (NN + 63) / 64;

  // --- Layer 1: f0 = x(bf16); hop1 finalizes edge weights (FINW) ---
  hop_kernel<0, 5, true><<<gHop, 256, 0, stream>>>();
  hop_kernel<5, 6, false><<<gHop, 256, 0, stream>>>();
  hop_kernel<6, 7, false><<<gHop, 256, 0, stream>>>();
  gemm_kernel<0, 3, 1><<<gGemm, 256, 0, stream>>>(b1);

  // --- Layer 2: f0 = Hn0; GEMM fused with layer-3 Z GEMMs (Hn1 stays in LDS) ---
  hop_kernel<3, 5, false><<<gHop, 256, 0, stream>>>();
  hop_kernel<5, 6, false><<<gHop, 256, 0, stream>>>();
  hop_kernel<6, 7, false><<<gHop, 256, 0, stream>>>();
  gemm2z_kernel<<<gGemm, 256, 0, stream>>>(b2, b3);  // -> Z3,Z2 (Hn1), Z1,Z0 (X16)

  // --- Layer 3 (Horner): out = Z0+b3 + A(Z1 + A(Z2 + A Z3)) ---
  hop64_kernel<8, 9, 12, false><<<gHop64, 256, 0, stream>>>(nullptr);   // T1 = A Z3 + Z2
  hop64_kernel<12, 10, 13, false><<<gHop64, 256, 0, stream>>>(nullptr); // T2 = A T1 + Z1
  hop64_kernel<13, 11, 12, true><<<gHop64, 256, 0, stream>>>(d_out);    // h = A T2 + Z0

  // --- Predictor (pos+neg fused, MFMA) ---
  predictor_kernel<<<(2 * PP) / (4 * 16), 256, 0, stream>>>(pos_src, pos_dst, neg_src, neg_dst,
                                                            pb1, P2, pb2, P3, pb3, d_out);
}

// Round 10
// 437.971 us; speedup vs baseline: 1.0532x; 1.0532x over previous
//
#include <hip/hip_runtime.h>
#include <hip/hip_bf16.h>

typedef unsigned short u16;
typedef unsigned int u32;
typedef short short8v __attribute__((ext_vector_type(8)));
typedef float f32x4 __attribute__((ext_vector_type(4)));
typedef u32 u32x4 __attribute__((ext_vector_type(4)));

#define NN 50000
#define EE 800000
#define PP 65536
#define NBKT 196      // node buckets of 256: ceil(NN/256)
#define NHB 256       // histogram blocks (edge chunks of 3125)
#define ECH 3125      // edges per histogram block: 256*3125 = EE exactly

// ---- static device workspace. RULE (r3): device-global addresses never cross
// the host/device boundary — kernels resolve them via compile-time IDs.
// RULE (r15): NO cooperative launch / grid.sync on this chip.
// RULE (r22): fused producer->consumer kernels must write into buffers that NO
// other block still reads.
__device__ __align__(256) float g_deg_norm[NN];
__device__ __align__(256) int   g_row_ptr[NN + 1];
__device__ __align__(256) int   g_rank[EE];          // intra-node rank
__device__ __align__(256) int   g_bh[NBKT * NHB];    // [bucket][block] counts
__device__ __align__(256) int   g_bbase[NBKT * NHB]; // exclusive scan over blocks
__device__ __align__(256) int   g_btot[NBKT];
__device__ __align__(256) u32   g_ebkt[EE];          // bucket-grouped: src | dlow<<16
__device__ __align__(256) float g_wtmp[EE];          // raw w (f32), bucket-grouped
__device__ __align__(256) float g_w2[EE];            // raw w, CSR order
__device__ __align__(256) u32   g_ecwp[EE];          // final: src(16b) | w_bf16(16b)
__device__ __align__(256) u16   g_X16[NN * 128];     // x bf16; after gemm1: Z1|Z0
__device__ __align__(256) u16   g_H1[NN * 128];      // hop outs
__device__ __align__(256) u16   g_H2[NN * 128];
__device__ __align__(256) u16   g_H3[NN * 128];      // hop out; later T ping|pong
__device__ __align__(256) u16   g_Hn0[NN * 128];
__device__ __align__(256) u16   g_Hn1[NN * 128];     // Z3|Z2 (gemm2z output only)
__device__ __align__(256) u16   g_Hf16[NN * 64];     // final h (bf16), row-major
__device__ __align__(256) u16   g_Bf1[512 * 128];    // W in MFMA B-fragment order
__device__ __align__(256) u16   g_Bf2[512 * 128];
__device__ __align__(256) u16   g_Bf3[512 * 64];
__device__ __align__(256) u16   g_Pf1[4 * 64 * 8];   // P1 in B-frag order
__device__ int g_f32mode;  // 1 if harness float tensors are float32, 0 if bf16

__device__ __forceinline__ float bf2f(u16 u) {
  union { u32 i; float f; } v;
  v.i = ((u32)u) << 16;
  return v.f;
}
__device__ __forceinline__ u16 f2bf(float f) {
  u32 x = __float_as_uint(f);
  u32 r = (x + 0x7fffu + ((x >> 16) & 1u)) >> 16;  // RNE
  return (u16)r;
}
__device__ __forceinline__ float ldf(const void* p, int i, int m) {
  return m ? ((const float*)p)[i] : bf2f(((const u16*)p)[i]);
}

// buffer IDs: 0 = X16, 3 = Hn0, 5 = H1, 6 = H2, 7 = H3 (stride 128)
template <int ID>
__device__ __forceinline__ u16* sel_buf() {
  if (ID == 0) return g_X16;
  if (ID == 3) return g_Hn0;
  if (ID == 5) return g_H1;
  if (ID == 6) return g_H2;
  return g_H3;
}
// width-64 Z/T buffers for layer-3 Horner (r22 alias-free mapping).
template <int ID>
__device__ __forceinline__ u16* zb() {
  if (ID == 8) return g_Hn1;                // Z3
  if (ID == 9) return g_Hn1 + NN * 64;      // Z2
  if (ID == 10) return g_X16;               // Z1
  if (ID == 11) return g_X16 + NN * 64;     // Z0 (+bias)
  if (ID == 12) return g_H3;                // T ping
  return g_H3 + NN * 64;                    // 13: T pong
}

// ---- per-block dtype vote (r22-proven)
__device__ __forceinline__ int vote_f32mode(const u16* __restrict__ x, int tid, int* vcnt) {
  if (tid == 0) *vcnt = 0;
  __syncthreads();
  u16 u = x[2 * (tid * 8)];
  if (((u >> 7) & 0xFF) >= 0x8F) atomicAdd(vcnt, 1);
  __syncthreads();
  return (*vcnt > 28) ? 1 : 0;
}

// ---------------- fused prep1: dtype vote | x->bf16 | bucket hist | W/P convert
template <int FOUT>
__device__ __forceinline__ void conv_w_body(const void* W, u16* dstbuf, int t, int m) {
  constexpr int NT = FOUT / 16;
  if (t >= 1024 * NT) return;
  int lane = t & 63;
  int rest = t >> 6;
  int nt = rest % NT;
  int s = (rest / NT) % 4;
  int kc = rest / (NT * 4);
  int kbase = kc * 128 + s * 32 + ((lane >> 4) << 3);
  int n = nt * 16 + (lane & 15);
  u16* dst = dstbuf + (size_t)t * 8;
#pragma unroll
  for (int j = 0; j < 8; ++j) dst[j] = f2bf(ldf(W, (kbase + j) * FOUT + n, m));
}
__global__ void prep1_kernel(const void* __restrict__ xv, const int* __restrict__ dst,
                             const void* __restrict__ W1, const void* __restrict__ W2,
                             const void* __restrict__ W3, const void* __restrict__ P1) {
  __shared__ int lhist[NBKT];
  __shared__ int vcnt;
  const u16* x = (const u16*)xv;
  int b = blockIdx.x, tid = threadIdx.x;
  int m = vote_f32mode(x, tid, &vcnt);
  if (b == 0 && tid == 0) g_f32mode = m;  // publish for downstream launches
  if (b < 12500) {
    int i = b * 256 + tid;  // u32-pair index, exact: 12500*256 = NN*64
    u32 lo = f2bf(ldf(x, 2 * i, m));
    u32 hi = f2bf(ldf(x, 2 * i + 1, m));
    ((u32*)g_X16)[i] = lo | (hi << 16);
  } else if (b < 12500 + NHB) {
    int hb = b - 12500;
    for (int i = tid; i < NBKT; i += 256) lhist[i] = 0;
    __syncthreads();
    int base = hb * ECH;
    for (int i = tid; i < ECH; i += 256) atomicAdd(&lhist[dst[base + i] >> 8], 1);
    __syncthreads();
    if (tid < NBKT) g_bh[tid * NHB + hb] = lhist[tid];
  } else {
    int wb = b - (12500 + NHB);
    if (wb < 32) {
      conv_w_body<128>(W1, g_Bf1, wb * 256 + tid, m);
    } else if (wb < 64) {
      conv_w_body<128>(W2, g_Bf2, (wb - 32) * 256 + tid, m);
    } else if (wb < 80) {
      conv_w_body<64>(W3, g_Bf3, (wb - 64) * 256 + tid, m);
    } else {
      int f = tid >> 6, lane = tid & 63;
      int ks = f >> 1, nt = f & 1;
      int quad = lane >> 4, arow = lane & 15;
#pragma unroll
      for (int j = 0; j < 8; ++j)
        g_Pf1[(size_t)tid * 8 + j] =
            f2bf(ldf(P1, (ks * 32 + quad * 8 + j) * 32 + nt * 16 + arow, m));
    }
  }
}

// ------------------------------------- S2: per-bucket exclusive scan over blocks
__global__ __launch_bounds__(256) void bucket_scan_kernel() {
  __shared__ int ws[4];
  int g = blockIdx.x, t = threadIdx.x;
  int v = g_bh[g * NHB + t];
  int x = v;
#pragma unroll
  for (int off = 1; off < 64; off <<= 1) {
    int y = __shfl_up(x, off, 64);
    if ((t & 63) >= off) x += y;
  }
  if ((t & 63) == 63) ws[t >> 6] = x;
  __syncthreads();
  int wp = 0;
  if (t >= 64) wp += ws[0];
  if (t >= 128) wp += ws[1];
  if (t >= 192) wp += ws[2];
  g_bbase[g * NHB + t] = wp + x - v;  // exclusive within bucket, block order
  if (t == 255) g_btot[g] = wp + x;
}

// --- local bucket-start scan helper: exclusive scan of g_btot into sb[] (LDS)
__device__ __forceinline__ void local_bstart(int* sb, int* ws, int tid) {
  int v = (tid < NBKT) ? g_btot[tid] : 0;
  int x = v;
#pragma unroll
  for (int off = 1; off < 64; off <<= 1) {
    int y = __shfl_up(x, off, 64);
    if ((tid & 63) >= off) x += y;
  }
  if ((tid & 63) == 63) ws[tid >> 6] = x;
  __syncthreads();
  int wp = 0;
  if (tid >= 64) wp += ws[0];
  if (tid >= 128) wp += ws[1];
  if (tid >= 192) wp += ws[2];
  if (tid < NBKT) sb[tid] = wp + x - v;
  if (tid == 0) sb[NBKT] = EE;
  __syncthreads();
}

// ---------------------------- S4: scatter edges into bucket-grouped order
__global__ __launch_bounds__(256) void scatter_bucket_kernel(const int* __restrict__ src,
                                                             const int* __restrict__ dst,
                                                             const void* __restrict__ w_edge) {
  __shared__ int sb[NBKT + 1];
  __shared__ int ws[4];
  __shared__ int lhist[NBKT];
  __shared__ int lbase[NBKT];
  int m = g_f32mode;
  int b = blockIdx.x, tid = threadIdx.x;
  local_bstart(sb, ws, tid);
  for (int i = tid; i < NBKT; i += 256) {
    lhist[i] = 0;
    lbase[i] = sb[i] + g_bbase[i * NHB + b];
  }
  __syncthreads();
  int base = b * ECH;
  for (int i = tid; i < ECH; i += 256) {
    int e = base + i;
    int d = dst[e];
    int s = src[e];
    float w = ldf(w_edge, e, m);
    int bkt = d >> 8;
    int r = atomicAdd(&lhist[bkt], 1);
    int pos = lbase[bkt] + r;
    g_ebkt[pos] = (u32)s | ((u32)(d & 255) << 16);
    g_wtmp[pos] = w;
  }
}

// ------------- S5: per-bucket CSR finalize: 256-bin LDS hist -> row_ptr,
// deg_norm, and in-bucket scatter to exact per-node segments.
__global__ __launch_bounds__(256) void csr_finalize_kernel() {
  __shared__ int sb[NBKT + 1];
  __shared__ int ws[4];
  __shared__ int hist[256];
  __shared__ int loff[256];
  int g = blockIdx.x, t = threadIdx.x;
  local_bstart(sb, ws, t);
  int bs = sb[g], be = sb[g + 1];
  hist[t] = 0;
  __syncthreads();
  for (int i = bs + t; i < be; i += 256) {
    int dlow = (g_ebkt[i] >> 16) & 0xFF;
    g_rank[i] = atomicAdd(&hist[dlow], 1);
  }
  __syncthreads();
  int v = hist[t];
  int x = v;
#pragma unroll
  for (int off = 1; off < 64; off <<= 1) {
    int y = __shfl_up(x, off, 64);
    if ((t & 63) >= off) x += y;
  }
  if ((t & 63) == 63) ws[t >> 6] = x;
  __syncthreads();
  int wp = 0;
  if (t >= 64) wp += ws[0];
  if (t >= 128) wp += ws[1];
  if (t >= 192) wp += ws[2];
  int excl = wp + x - v;
  loff[t] = excl;
  int node = g * 256 + t;
  if (node < NN) {
    g_row_ptr[node] = bs + excl;
    g_deg_norm[node] = rsqrtf((float)(v > 0 ? v : 1));
  }
  if (g == NBKT - 1 && t == 0) g_row_ptr[NN] = EE;
  __syncthreads();
  for (int i = bs + t; i < be; i += 256) {
    u32 p = g_ebkt[i];
    int dlow = (p >> 16) & 0xFF;
    int pos = bs + loff[dlow] + g_rank[i];
    g_ecwp[pos] = p;       // src in low 16; w field written by hop1 (FINW)
    g_w2[pos] = g_wtmp[i];
  }
}

// --------------------------------------------------------- width-128 hop (r21)
// ONE 16-LANE GROUP PER NODE (4 nodes/wave); per-lane register accumulators.
template <int IN_ID, int OUT_ID, bool FINW>
__global__ __launch_bounds__(256) void hop_kernel() {
  int lane = threadIdx.x & 63;
  int wv = threadIdx.x >> 6;
  int grp = lane >> 4;  // node slot in wave
  int q = lane & 15;    // feature block
  int n = blockIdx.x * 16 + wv * 4 + grp;  // NN%16==0 -> no OOB (grid exact)
  const u16* inf = sel_buf<IN_ID>() + q * 8;
  int beg = g_row_ptr[n], end = g_row_ptr[n + 1];
  int sl = grp << 4;  // shfl base lane of this group
  float a[8];
#pragma unroll
  for (int j = 0; j < 8; ++j) a[j] = 0.f;
  for (int c = beg; c < end; c += 16) {
    int cnt = end - c;
    if (cnt > 16) cnt = 16;
    u32 myp = 0;
    float wf = 0.f;
    if (q < cnt) {
      myp = g_ecwp[c + q];
      if (FINW) {
        wf = g_w2[c + q] * g_deg_norm[myp & 0xFFFFu];
        g_ecwp[c + q] = (myp & 0xFFFFu) | ((u32)f2bf(wf) << 16);
      } else {
        wf = bf2f((u16)(myp >> 16));
      }
    }
    int i = 0;
    for (; i + 4 <= cnt; i += 4) {
      u32 p0 = __shfl(myp, sl + i, 64);
      u32 p1 = __shfl(myp, sl + i + 1, 64);
      u32 p2 = __shfl(myp, sl + i + 2, 64);
      u32 p3 = __shfl(myp, sl + i + 3, 64);
      float w0 = __shfl(wf, sl + i, 64);
      float w1 = __shfl(wf, sl + i + 1, 64);
      float w2 = __shfl(wf, sl + i + 2, 64);
      float w3 = __shfl(wf, sl + i + 3, 64);
      short8v u0 = *(const short8v*)(inf + (p0 & 0xFFFFu) * 128);
      short8v u1 = *(const short8v*)(inf + (p1 & 0xFFFFu) * 128);
      short8v u2 = *(const short8v*)(inf + (p2 & 0xFFFFu) * 128);
      short8v u3 = *(const short8v*)(inf + (p3 & 0xFFFFu) * 128);
#pragma unroll
      for (int j = 0; j < 8; ++j) {
        a[j] += w0 * bf2f((u16)u0[j]);
        a[j] += w1 * bf2f((u16)u1[j]);
        a[j] += w2 * bf2f((u16)u2[j]);
        a[j] += w3 * bf2f((u16)u3[j]);
      }
    }
    for (; i < cnt; ++i) {
      u32 p = __shfl(myp, sl + i, 64);
      float w = __shfl(wf, sl + i, 64);
      short8v u = *(const short8v*)(inf + (p & 0xFFFFu) * 128);
#pragma unroll
      for (int j = 0; j < 8; ++j) a[j] += w * bf2f((u16)u[j]);
    }
  }
  float dn = g_deg_norm[n];
  u32x4 o;
#pragma unroll
  for (int j = 0; j < 4; ++j)
    o[j] = (u32)f2bf(a[2 * j] * dn) | ((u32)f2bf(a[2 * j + 1] * dn) << 16);
  *(u32x4*)(sel_buf<OUT_ID>() + n * 128 + q * 8) = o;  // 16B/lane, 1KB/wave
}

// ------------------------------------------------- width-64 hop with addend
template <int IN_ID, int ADD_ID, int OUT_ID, bool FINAL>
__global__ __launch_bounds__(256) void hop64_kernel(void* __restrict__ outp) {
  int lane = threadIdx.x & 63;
  int wv = threadIdx.x >> 6;
  int grp = lane >> 3;  // node slot 0..7
  int q = lane & 7;     // feature block (8 x 8 = 64 feats)
  int n = blockIdx.x * 32 + wv * 8 + grp;
  if (n >= NN) return;  // no barriers -> safe
  const u16* inf = zb<IN_ID>() + q * 8;
  int beg = g_row_ptr[n], end = g_row_ptr[n + 1];
  int sl = grp << 3;
  float a[8];
#pragma unroll
  for (int j = 0; j < 8; ++j) a[j] = 0.f;
  for (int c = beg; c < end; c += 8) {
    int cnt = end - c;
    if (cnt > 8) cnt = 8;
    u32 myp = 0;
    float wf = 0.f;
    if (q < cnt) {
      myp = g_ecwp[c + q];
      wf = bf2f((u16)(myp >> 16));
    }
    int i = 0;
    for (; i + 4 <= cnt; i += 4) {
      u32 p0 = __shfl(myp, sl + i, 64);
      u32 p1 = __shfl(myp, sl + i + 1, 64);
      u32 p2 = __shfl(myp, sl + i + 2, 64);
      u32 p3 = __shfl(myp, sl + i + 3, 64);
      float w0 = __shfl(wf, sl + i, 64);
      float w1 = __shfl(wf, sl + i + 1, 64);
      float w2 = __shfl(wf, sl + i + 2, 64);
      float w3 = __shfl(wf, sl + i + 3, 64);
      short8v u0 = *(const short8v*)(inf + (p0 & 0xFFFFu) * 64);
      short8v u1 = *(const short8v*)(inf + (p1 & 0xFFFFu) * 64);
      short8v u2 = *(const short8v*)(inf + (p2 & 0xFFFFu) * 64);
      short8v u3 = *(const short8v*)(inf + (p3 & 0xFFFFu) * 64);
#pragma unroll
      for (int j = 0; j < 8; ++j) {
        a[j] += w0 * bf2f((u16)u0[j]);
        a[j] += w1 * bf2f((u16)u1[j]);
        a[j] += w2 * bf2f((u16)u2[j]);
        a[j] += w3 * bf2f((u16)u3[j]);
      }
    }
    for (; i < cnt; ++i) {
      u32 p = __shfl(myp, sl + i, 64);
      float w = __shfl(wf, sl + i, 64);
      short8v u = *(const short8v*)(inf + (p & 0xFFFFu) * 64);
#pragma unroll
      for (int j = 0; j < 8; ++j) a[j] += w * bf2f((u16)u[j]);
    }
  }
  float dn = g_deg_norm[n];
  int ci = n * 64 + q * 8;
  u32x4 ad = *(const u32x4*)(zb<ADD_ID>() + ci);
  float r[8];
#pragma unroll
  for (int j = 0; j < 4; ++j) {
    r[2 * j] = a[2 * j] * dn + bf2f((u16)ad[j]);
    r[2 * j + 1] = a[2 * j + 1] * dn + bf2f((u16)(ad[j] >> 16));
  }
  u32x4 o;
#pragma unroll
  for (int j = 0; j < 4; ++j)
    o[j] = (u32)f2bf(r[2 * j]) | ((u32)f2bf(r[2 * j + 1]) << 16);
  if (!FINAL) {
    *(u32x4*)(zb<OUT_ID>() + ci) = o;
  } else {
    *(u32x4*)(g_Hf16 + ci) = o;
    if (g_f32mode) {
#pragma unroll
      for (int j = 0; j < 8; ++j) ((float*)outp)[2 * PP + ci + j] = r[j];
    } else {
      *(u32x4*)((u16*)outp + 2 * PP + ci) = o;
    }
  }
}

// -------------------------------------------------- MFMA GEMM layer-1 (r23)
// C = ReLU([X16|H1|H2|H3] @ Bf1 + b1) -> Hn0. B staged in LDS per kc chunk
// (32 KB contiguous) so 4 waves share one B read instead of 4 independent
// L2 streams (r9 PMC: MfmaUtil 7%, latency-bound on per-wave B loads).
__global__ __launch_bounds__(256) void gemm1_kernel(const void* __restrict__ bias) {
  __shared__ __align__(16) u16 sB[16384];  // 32 KB = one kc chunk of Bf1
  constexpr int NT = 8;
  int tid = threadIdx.x;
  int lane = tid & 63, wv = tid >> 6;
  int quad = lane >> 4, arow = lane & 15;
  int mbase = blockIdx.x * 64 + wv * 16;
  bool active = (mbase < NN);  // NN % 16 == 0; all threads reach barriers
  int row0 = mbase + arow;

  f32x4 acc[NT];
#pragma unroll
  for (int nt = 0; nt < NT; ++nt) acc[nt] = (f32x4){0.f, 0.f, 0.f, 0.f};

  for (int kc = 0; kc < 4; ++kc) {
    {  // cooperative stage: 2048 u32x4, 8 per thread
      const u32x4* srcv = (const u32x4*)(g_Bf1 + kc * 16384);
      u32x4* dstv = (u32x4*)sB;
#pragma unroll
      for (int j = 0; j < 8; ++j) dstv[tid + j * 256] = srcv[tid + j * 256];
    }
    __syncthreads();
    if (active) {
      const u16* Abase = (kc == 0) ? g_X16 : (kc == 1) ? g_H1 : (kc == 2) ? g_H2 : g_H3;
#pragma unroll
      for (int s = 0; s < 4; ++s) {
        short8v av = *(const short8v*)(Abase + row0 * 128 + s * 32 + quad * 8);
        const u16* bp = sB + (size_t)((s * NT) * 64 + lane) * 8;
#pragma unroll
        for (int nt = 0; nt < NT; ++nt) {
          short8v b = *(const short8v*)(bp + nt * 64 * 8);
          acc[nt] = __builtin_amdgcn_mfma_f32_16x16x32_bf16(av, b, acc[nt], 0, 0, 0);
        }
      }
    }
    __syncthreads();
  }

  if (active) {
    int m = g_f32mode;
    float bn[NT];
#pragma unroll
    for (int nt = 0; nt < NT; ++nt) bn[nt] = ldf(bias, nt * 16 + arow, m);
#pragma unroll
    for (int i = 0; i < 4; ++i) {
      int row = mbase + quad * 4 + i;  // C/D: col=lane&15, row=quad*4+reg
#pragma unroll
      for (int nt = 0; nt < NT; ++nt) {
        float v = acc[nt][i] + bn[nt];
        v = v > 0.f ? v : 0.f;  // ReLU
        g_Hn0[row * 128 + nt * 16 + arow] = f2bf(v);
      }
    }
  }
}

// ------------------ fused layer-2 GEMM + Z_k GEMMs (r23: + B LDS staging)
// Phase A: Hn1-tile = ReLU([Hn0|H1|H2|H3] @ Bf2 + b2), Bf2 staged per-kc.
// Phase B: Z_k = Hn1-tile @ W3[kc] (+b3 k=0); Bf3 staged in 2 x 32 KB halves
// reusing sB. Z3/Z2 -> g_Hn1, Z1/Z0 -> g_X16 (alias-free, r22).
__global__ __launch_bounds__(256) void gemm2z_kernel(const void* __restrict__ bias2,
                                                     const void* __restrict__ bias3) {
  __shared__ __align__(16) u16 lt[4][16][136];  // 17408 B
  __shared__ __align__(16) u16 sB[16384];       // 32 KB staging (B2 chunk / B3 half)
  constexpr int NT = 8;
  int tid = threadIdx.x;
  int lane = tid & 63, wv = tid >> 6;
  int quad = lane >> 4, arow = lane & 15;
  int mbase = blockIdx.x * 64 + wv * 16;
  bool active = (mbase < NN);  // NN % 16 == 0
  int row0 = mbase + arow;
  int m = g_f32mode;

  // ---- phase A: layer-2 GEMM into own LDS slice ----
  f32x4 acc[NT];
#pragma unroll
  for (int nt = 0; nt < NT; ++nt) acc[nt] = (f32x4){0.f, 0.f, 0.f, 0.f};
  for (int kc = 0; kc < 4; ++kc) {
    {
      const u32x4* srcv = (const u32x4*)(g_Bf2 + kc * 16384);
      u32x4* dstv = (u32x4*)sB;
#pragma unroll
      for (int j = 0; j < 8; ++j) dstv[tid + j * 256] = srcv[tid + j * 256];
    }
    __syncthreads();
    if (active) {
      const u16* Abase = (kc == 0) ? g_Hn0 : (kc == 1) ? g_H1 : (kc == 2) ? g_H2 : g_H3;
#pragma unroll
      for (int s = 0; s < 4; ++s) {
        short8v av = *(const short8v*)(Abase + row0 * 128 + s * 32 + quad * 8);
        const u16* bp = sB + (size_t)((s * NT) * 64 + lane) * 8;
#pragma unroll
        for (int nt = 0; nt < NT; ++nt) {
          short8v b = *(const short8v*)(bp + nt * 64 * 8);
          acc[nt] = __builtin_amdgcn_mfma_f32_16x16x32_bf16(av, b, acc[nt], 0, 0, 0);
        }
      }
    }
    __syncthreads();
  }
  if (active) {
    float bn[NT];
#pragma unroll
    for (int nt = 0; nt < NT; ++nt) bn[nt] = ldf(bias2, nt * 16 + arow, m);
#pragma unroll
    for (int i = 0; i < 4; ++i) {
#pragma unroll
      for (int nt = 0; nt < NT; ++nt) {
        float v = acc[nt][i] + bn[nt];
        v = v > 0.f ? v : 0.f;  // ReLU
        lt[wv][quad * 4 + i][nt * 16 + arow] = f2bf(v);
      }
    }
  }

  // ---- phase B: Z_k = tile @ W3[kc], Bf3 staged in two 32 KB halves ----
  f32x4 az[4][4];  // [kc][nt]
#pragma unroll
  for (int kc = 0; kc < 4; ++kc)
#pragma unroll
    for (int nt = 0; nt < 4; ++nt) az[kc][nt] = (f32x4){0.f, 0.f, 0.f, 0.f};
  for (int half = 0; half < 2; ++half) {
    __syncthreads();  // protects lt (half 0) / prior sB reads (half 1)
    {
      const u32x4* srcv = (const u32x4*)(g_Bf3 + half * 16384);
      u32x4* dstv = (u32x4*)sB;
#pragma unroll
      for (int j = 0; j < 8; ++j) dstv[tid + j * 256] = srcv[tid + j * 256];
    }
    __syncthreads();
    if (active) {
#pragma unroll
      for (int k2 = 0; k2 < 2; ++k2) {
        int kc = half * 2 + k2;
#pragma unroll
        for (int s = 0; s < 4; ++s) {
          short8v av = *(const short8v*)&lt[wv][arow][s * 32 + quad * 8];
          const u16* bp = sB + (size_t)(((k2 * 4 + s) * 4) * 64 + lane) * 8;
#pragma unroll
          for (int nt = 0; nt < 4; ++nt) {
            short8v b = *(const short8v*)(bp + nt * 64 * 8);
            az[kc][nt] = __builtin_amdgcn_mfma_f32_16x16x32_bf16(av, b, az[kc][nt], 0, 0, 0);
          }
        }
      }
    }
  }
  if (active) {
    float b3n[4];
#pragma unroll
    for (int nt = 0; nt < 4; ++nt) b3n[nt] = ldf(bias3, nt * 16 + arow, m);
#pragma unroll
    for (int kc = 0; kc < 4; ++kc) {
      u16* Z = (kc == 0) ? zb<11>() : (kc == 1) ? zb<10>() : (kc == 2) ? zb<9>() : zb<8>();
#pragma unroll
      for (int i = 0; i < 4; ++i) {
        int row = mbase + quad * 4 + i;
#pragma unroll
        for (int nt = 0; nt < 4; ++nt) {
          float v = az[kc][nt][i] + (kc == 0 ? b3n[nt] : 0.f);
          Z[row * 64 + nt * 16 + arow] = f2bf(v);
        }
      }
    }
  }
}

// ------------------------------------------------------------------ predictor
__global__ __launch_bounds__(256) void predictor_kernel(
    const int* __restrict__ pos_src, const int* __restrict__ pos_dst,
    const int* __restrict__ neg_src, const int* __restrict__ neg_dst,
    const void* __restrict__ pb1, const void* __restrict__ P2,
    const void* __restrict__ pb2, const void* __restrict__ P3, const void* __restrict__ pb3,
    void* __restrict__ out) {
  __shared__ float sP2[32 * 16];
  __shared__ float sb1[32], sb2[16], sP3[16];
  __shared__ float sb3;
  __shared__ float zt[4][16][33];
  int m = g_f32mode;
  int tid = threadIdx.x;
  for (int i = tid; i < 512; i += 256) sP2[i] = ldf(P2, i, m);
  if (tid < 32) sb1[tid] = ldf(pb1, tid, m);
  if (tid < 16) sb2[tid] = ldf(pb2, tid, m);
  if (tid < 16) sP3[tid] = ldf(P3, tid, m);
  if (tid == 0) sb3 = ldf(pb3, 0, m);
  __syncthreads();

  int wv = tid >> 6, lane = tid & 63;
  int quad = lane >> 4, arow = lane & 15;
  int base = (blockIdx.x * 4 + wv) * 16;
  int idx = base + arow;
  int s, d;
  if (idx < PP) { s = pos_src[idx]; d = pos_dst[idx]; }  // PP%16==0 -> wave-uniform
  else          { s = neg_src[idx - PP]; d = neg_dst[idx - PP]; }

  const u16* hs = g_Hf16 + s * 64 + quad * 8;
  const u16* hd = g_Hf16 + d * 64 + quad * 8;
  short8v zf[2];
#pragma unroll
  for (int ks = 0; ks < 2; ++ks) {
    short8v a = *(const short8v*)(hs + ks * 32);
    short8v b = *(const short8v*)(hd + ks * 32);
#pragma unroll
    for (int j = 0; j < 8; ++j)
      ((u16*)&zf[ks])[j] = f2bf(bf2f((u16)a[j]) * bf2f((u16)b[j]));
  }
  f32x4 acc[2];
  acc[0] = (f32x4){0.f, 0.f, 0.f, 0.f};
  acc[1] = (f32x4){0.f, 0.f, 0.f, 0.f};
#pragma unroll
  for (int ks = 0; ks < 2; ++ks) {
#pragma unroll
    for (int nt = 0; nt < 2; ++nt) {
      short8v bfr = *(const short8v*)(g_Pf1 + (size_t)((ks * 2 + nt) * 64 + lane) * 8);
      acc[nt] = __builtin_amdgcn_mfma_f32_16x16x32_bf16(zf[ks], bfr, acc[nt], 0, 0, 0);
    }
  }
#pragma unroll
  for (int nt = 0; nt < 2; ++nt) {
    float bn = sb1[nt * 16 + arow];
#pragma unroll
    for (int i = 0; i < 4; ++i) {
      float v = acc[nt][i] + bn;
      zt[wv][quad * 4 + i][nt * 16 + arow] = v > 0.f ? v : 0.2f * v;
    }
  }
  __syncthreads();
  float z2[4];
#pragma unroll
  for (int jj = 0; jj < 4; ++jj) z2[jj] = sb2[quad * 4 + jj];
  const float* zrow = &zt[wv][arow][0];
#pragma unroll
  for (int c = 0; c < 32; ++c) {
    float zc = zrow[c];
#pragma unroll
    for (int jj = 0; jj < 4; ++jj) z2[jj] += zc * sP2[c * 16 + quad * 4 + jj];
  }
  float o = 0.f;
#pragma unroll
  for (int jj = 0; jj < 4; ++jj) {
    float v = z2[jj] > 0.f ? z2[jj] : 0.2f * z2[jj];
    o += v * sP3[quad * 4 + jj];
  }
  o += __shfl_xor(o, 16, 64);
  o += __shfl_xor(o, 32, 64);
  o += sb3;
  if (quad == 0) {
    if (m) ((float*)out)[idx] = o;
    else   ((u16*)out)[idx] = f2bf(o);
  }
}

// ------------------------------------------------------------------- launch
extern "C" void kernel_launch(void* const* d_in, const int* in_sizes, int n_in,
                              void* d_out, int out_size, void* d_ws, size_t ws_size,
                              hipStream_t stream) {
  const void* x      = d_in[0];
  const int* src     = (const int*)d_in[1];
  const int* dst     = (const int*)d_in[2];
  const void* w_edge = d_in[3];
  const int* pos_src = (const int*)d_in[4];
  const int* pos_dst = (const int*)d_in[5];
  const int* neg_src = (const int*)d_in[6];
  const int* neg_dst = (const int*)d_in[7];
  const void* W1 = d_in[8];
  const void* b1 = d_in[9];
  const void* W2 = d_in[10];
  const void* b2 = d_in[11];
  const void* W3 = d_in[12];
  const void* b3 = d_in[13];
  const void* P1  = d_in[14];
  const void* pb1 = d_in[15];
  const void* P2  = d_in[16];
  const void* pb2 = d_in[17];
  const void* P3  = d_in[18];
  const void* pb3 = d_in[19];
  (void)d_ws; (void)ws_size; (void)in_sizes; (void)n_in; (void)out_size;

  // --- atomic-free CSR build; dtype vote folded into prep1 (r22) ---
  prep1_kernel<<<12500 + NHB + 81, 256, 0, stream>>>(x, dst, W1, W2, W3, P1);
  bucket_scan_kernel<<<NBKT, 256, 0, stream>>>();
  scatter_bucket_kernel<<<NHB, 256, 0, stream>>>(src, dst, w_edge);
  csr_finalize_kernel<<<NBKT, 256, 0, stream>>>();

  int gHop = NN / 16;            // 3125, exact (16 nodes/block)
  int gHop64 = (NN + 31) / 32;   // 1563 (32 nodes/block)
  int gGemm = (NN + 63) / 64;

  // --- Layer 1: f0 = x(bf16); hop1 finalizes edge weights (FINW) ---
  hop_kernel<0, 5, true><<<gHop, 256, 0, stream>>>();
  hop_kernel<5, 6, false><<<gHop, 256, 0, stream>>>();
  hop_kernel<6, 7, false><<<gHop, 256, 0, stream>>>();
  gemm1_kernel<<<gGemm, 256, 0, stream>>>(b1);

  // --- Layer 2: f0 = Hn0; GEMM fused with layer-3 Z GEMMs (Hn1 stays in LDS) ---
  hop_kernel<3, 5, false><<<gHop, 256, 0, stream>>>();
  hop_kernel<5, 6, false><<<gHop, 256, 0, stream>>>();
  hop_kernel<6, 7, false><<<gHop, 256, 0, stream>>>();
  gemm2z_kernel<<<gGemm, 256, 0, stream>>>(b2, b3);  // -> Z3,Z2 (Hn1), Z1,Z0 (X16)

  // --- Layer 3 (Horner): out = Z0+b3 + A(Z1 + A(Z2 + A Z3)) ---
  hop64_kernel<8, 9, 12, false><<<gHop64, 256, 0, stream>>>(nullptr);   // T1 = A Z3 + Z2
  hop64_kernel<12, 10, 13, false><<<gHop64, 256, 0, stream>>>(nullptr); // T2 = A T1 + Z1
  hop64_kernel<13, 11, 12, true><<<gHop64, 256, 0, stream>>>(d_out);    // h = A T2 + Z0

  // --- Predictor (pos+neg fused, MFMA) ---
  predictor_kernel<<<(2 * PP) / (4 * 16), 256, 0, stream>>>(pos_src, pos_dst, neg_src, neg_dst,
                                                            pb1, P2, pb2, P3, pb3, d_out);
}